// Round 11
// baseline (1956.234 us; speedup 1.0000x reference)
//
#include <hip/hip_runtime.h>
#include <math.h>

#define BB 16
#define SS 64
#define MM 2048
#define DD 256
#define TOPK 8
#define SCALE 0.0625f      // 1/sqrt(256)
#define MAXD 512

__device__ __forceinline__ float wave_sum(float p) {
    for (int o = 32; o; o >>= 1) p += __shfl_xor(p, o);
    return p;
}

__device__ __forceinline__ void wave_argmax(float& v, int& i) {
    for (int o = 32; o; o >>= 1) {
        float ov = __shfl_xor(v, o);
        int oi = __shfl_xor(i, o);
        if (ov > v || (ov == v && oi < i)) { v = ov; i = oi; }
    }
}

// generic 32x32-tiled transpose: dst[c][r] = src[r][c]; grid=(C/32, R/32), block=256
__global__ __launch_bounds__(256) void k_tr(const float* __restrict__ src, float* __restrict__ dst,
                                            int sld, int dld) {
    __shared__ float ts[32][33];
    int c0 = blockIdx.x * 32, r0 = blockIdx.y * 32;
    int xx = threadIdx.x & 31, yy = threadIdx.x >> 5;
    for (int i = 0; i < 4; ++i)
        ts[yy + 8 * i][xx] = src[(size_t)(r0 + yy + 8 * i) * sld + c0 + xx];
    __syncthreads();
    for (int i = 0; i < 4; ++i)
        dst[(size_t)(c0 + yy + 8 * i) * dld + r0 + xx] = ts[xx][yy + 8 * i];
}

// C[i][j] = sum_d A[i][d]*B[d][j] (+bias[j]). grid = rows, block = 256
__global__ __launch_bounds__(256) void k_gemv(const float* __restrict__ A, const float* __restrict__ B,
                                              const float* __restrict__ bias, float* __restrict__ C) {
    const int i = blockIdx.x, tid = threadIdx.x;
    __shared__ float as[DD];
    as[tid] = A[(size_t)i * DD + tid];
    __syncthreads();
    float a0 = bias ? bias[tid] : 0.f, a1 = 0.f;
#pragma unroll 4
    for (int d = 0; d < DD; d += 2) {
        a0 = fmaf(as[d],     B[(size_t)d * DD + tid],       a0);
        a1 = fmaf(as[d + 1], B[(size_t)(d + 1) * DD + tid], a1);
    }
    C[(size_t)i * DD + tid] = a0 + a1;
}

// F[j][d] = sum_k Wu[j][256+k]*Wv[k][d];  cb[j] = sum_k bv[k]*Wu[j][256+k]. grid=256
__global__ __launch_bounds__(256) void k_fuse(const float* __restrict__ Wu, const float* __restrict__ Wv,
                                              const float* __restrict__ bv, float* __restrict__ F,
                                              float* __restrict__ cb) {
    const int j = blockIdx.x, tid = threadIdx.x;
    const float* wuh = Wu + (size_t)j * (2 * DD) + DD;
    float a0 = 0.f, a1 = 0.f;
#pragma unroll 4
    for (int k = 0; k < DD; k += 2) {
        a0 = fmaf(wuh[k],     Wv[(size_t)k * DD + tid],       a0);
        a1 = fmaf(wuh[k + 1], Wv[(size_t)(k + 1) * DD + tid], a1);
    }
    F[(size_t)j * DD + tid] = a0 + a1;
    if (tid < 64) {
        float4 b4 = ((const float4*)bv)[tid];
        float4 w4 = ((const float4*)wuh)[tid];
        float p = wave_sum(b4.x * w4.x + b4.y * w4.y + b4.z * w4.z + b4.w * w4.w);
        if (tid == 0) cb[j] = p;
    }
}

// E[bt][m] = exp(SCALE * sum_d QK[bt][d]*memT[d][m])   (q.bk dropped: softmax-invariant)
// grid=(MM/256, BB*SS/16), block=1024
__global__ __launch_bounds__(1024) void k_escore(const float* __restrict__ QK,
                                                 const float* __restrict__ memT,
                                                 float* __restrict__ E) {
    const int tid = threadIdx.x;
    const int mloc = tid & 255, bs = tid >> 8;
    const int m0 = blockIdx.x * 256, bt0 = blockIdx.y * 16;
    __shared__ float qkS[16][DD];
    for (int i = tid; i < 16 * DD; i += 1024)
        ((float*)qkS)[i] = QK[(size_t)bt0 * DD + i];
    __syncthreads();
    float acc0 = 0.f, acc1 = 0.f, acc2 = 0.f, acc3 = 0.f;
    const float* mp = memT + m0 + mloc;
    const int r0 = bs * 4;
#pragma unroll 4
    for (int d = 0; d < DD; ++d) {
        float v = mp[(size_t)d * MM];
        acc0 = fmaf(qkS[r0][d],     v, acc0);
        acc1 = fmaf(qkS[r0 + 1][d], v, acc1);
        acc2 = fmaf(qkS[r0 + 2][d], v, acc2);
        acc3 = fmaf(qkS[r0 + 3][d], v, acc3);
    }
    size_t ob = (size_t)(bt0 + r0) * MM + m0 + mloc;
    E[ob] = expf(acc0 * SCALE);          E[ob + MM] = expf(acc1 * SCALE);
    E[ob + 2 * MM] = expf(acc2 * SCALE); E[ob + 3 * MM] = expf(acc3 * SCALE);
}

// AM0[bt][d] = sum_m E[bt][m]*memory0[m][d].  grid=BB*SS/4 blocks, 4 bt each, block=1024
__global__ __launch_bounds__(1024) void k_am0(const float* __restrict__ E,
                                              const float* __restrict__ memory0,
                                              float* __restrict__ AM0) {
    __shared__ float eS[4][MM];          // 32 KB
    const int tid = threadIdx.x;
    const int bt0 = blockIdx.x * 4;
    for (int i = tid; i < 4 * MM; i += 1024)
        ((float*)eS)[i] = E[(size_t)bt0 * MM + i];
    __syncthreads();
    const int col = tid & 255, qq = tid >> 8;
    const float* mp = memory0 + col;
    const float* ep = eS[qq];
    float a0 = 0.f, a1 = 0.f;
#pragma unroll 4
    for (int m = 0; m < MM; m += 2) {
        a0 = fmaf(ep[m],     mp[(size_t)m * DD],       a0);
        a1 = fmaf(ep[m + 1], mp[(size_t)(m + 1) * DD], a1);
    }
    AM0[(size_t)(bt0 + qq) * DD + col] = a0 + a1;
}

// One block per batch, zero cross-block communication. All state in LDS.
__global__ __launch_bounds__(1024) void k_persist(
    const float* __restrict__ x, const float* __restrict__ memory0,
    const float* __restrict__ E, const float* __restrict__ AM0,
    const float* __restrict__ QK, const float* __restrict__ GXU,
    const float* __restrict__ F, const float* __restrict__ cb,
    float* __restrict__ dval, float* __restrict__ amAll) {
    const int b = blockIdx.x;
    const int tid = threadIdx.x, w = tid >> 6, lane = tid & 63;
    __shared__ float es[MM];             // 8 KB
    __shared__ float qks[DD], xs[DD], amS[DD], gs[DD];
    __shared__ float acc[16][DD];        // 16 KB per-wave correction accumulators
    __shared__ int   flag[MM];           // 8 KB: slot+1 or 0
    __shared__ short dirtyRow[MAXD];     // 1 KB
    __shared__ float candV[16 * TOPK];
    __shared__ int   candI[16 * TOPK];
    __shared__ float red16[16];
    __shared__ int   topI[TOPK], slotArr[TOPK], wasArr[TOPK];
    __shared__ int   ndS, slotCntS;

    flag[tid] = 0; flag[tid + 1024] = 0;
    if (tid == 0) { ndS = 0; slotCntS = 0; }
    __syncthreads();

    for (int t = 0; t < SS; ++t) {
        const int bt = (b << 6) + t;
        // ---- region 1: loads ----
        if (tid < DD) {
            qks[tid] = QK[(size_t)bt * DD + tid];
            xs[tid]  = x[(size_t)bt * DD + tid];
        }
        es[tid]        = E[(size_t)bt * MM + tid];
        es[tid + 1024] = E[(size_t)bt * MM + tid + 1024];
        ((float*)acc)[tid] = 0.f;        ((float*)acc)[tid + 1024] = 0.f;
        ((float*)acc)[tid + 2048] = 0.f; ((float*)acc)[tid + 3072] = 0.f;
        __syncthreads();
        const int nd = ndS;

        // ---- region 2: fused dirty pass (scores + am-corrections), wave per row ----
        {
            float4 q4 = ((const float4*)qks)[lane];
            for (int i = w; i < nd; i += 16) {
                int rl = dirtyRow[i];
                int slot = flag[rl] - 1;
                float4 dv = ((const float4*)(dval + ((size_t)(b * MAXD + slot)) * DD))[lane];
                float4 m0 = ((const float4*)(memory0 + (size_t)rl * DD))[lane];
                float p = wave_sum(dv.x * q4.x + dv.y * q4.y + dv.z * q4.z + dv.w * q4.w);
                float e = expf(p * SCALE);
                float eb = es[rl];               // all lanes read BEFORE lane0 writes
                float4 a = ((float4*)(acc[w]))[lane];
                a.x += e * dv.x - eb * m0.x;
                a.y += e * dv.y - eb * m0.y;
                a.z += e * dv.z - eb * m0.z;
                a.w += e * dv.w - eb * m0.w;
                ((float4*)(acc[w]))[lane] = a;
                if (lane == 0) es[rl] = e;
            }
        }
        __syncthreads();

        // ---- region 3: denom partials + per-wave top-8 over 128-slice ----
        {
            float s = wave_sum(es[tid] + es[tid + 1024]);
            if (lane == 0) red16[w] = s;
        }
        {
            float v0 = es[w * 128 + lane], v1 = es[w * 128 + 64 + lane];
            int i0 = w * 128 + lane, i1 = w * 128 + 64 + lane;
            for (int k = 0; k < TOPK; ++k) {
                float bb = v0; int bi = i0;
                if (v1 > v0 || (v1 == v0 && i1 < i0)) { bb = v1; bi = i1; }
                wave_argmax(bb, bi);
                if (lane == 0) { candV[w * TOPK + k] = bb; candI[w * TOPK + k] = bi; }
                if (i0 == bi) v0 = -1e30f;
                if (i1 == bi) v1 = -1e30f;
            }
        }
        __syncthreads();

        // ---- region 4: am combine + amAll store (tid<DD) ; topI merge (w15) ----
        if (tid < DD) {
            float tot = 0.f;
#pragma unroll
            for (int i2 = 0; i2 < 16; ++i2) tot += red16[i2];
            float c_ = 0.f;
#pragma unroll
            for (int ww = 0; ww < 16; ++ww) c_ += acc[ww][tid];
            float a = (AM0[(size_t)bt * DD + tid] + c_) / tot;
            amS[tid] = a;
            amAll[(size_t)bt * DD + tid] = a;
        }
        if (w == 15) {                   // merge 128 candidates -> global top-8
            float v0 = candV[lane], v1 = candV[64 + lane];
            int i0 = candI[lane], i1 = candI[64 + lane];
            for (int k = 0; k < TOPK; ++k) {
                float bb = v0; int bi = i0;
                if (v1 > v0 || (v1 == v0 && i1 < i0)) { bb = v1; bi = i1; }
                wave_argmax(bb, bi);
                if (lane == 0) topI[k] = bi;
                if (i0 == bi) v0 = -1e30f;
                if (i1 == bi) v1 = -1e30f;
            }
        }
        __syncthreads();

        // ---- region 5: gate (16 j per wave) + bookkeeping (w0 lanes<8) ----
        if (w == 0 && lane < TOPK) {
            int row = topI[lane];
            int fs = flag[row];
            int slot, wd = (fs != 0);
            if (!wd) {
                slot = atomicAdd(&slotCntS, 1);
                flag[row] = slot + 1;
                int idx = atomicAdd(&ndS, 1);
                dirtyRow[idx] = (short)row;
            } else slot = fs - 1;
            slotArr[lane] = slot; wasArr[lane] = wd;
        }
        {
            float4 a4 = ((const float4*)amS)[lane];
            for (int i = 0; i < 16; ++i) {
                int j = i * 16 + w;
                float4 f4 = ((const float4*)(F + (size_t)j * DD))[lane];
                float pg = wave_sum(f4.x * a4.x + f4.y * a4.y + f4.z * a4.z + f4.w * a4.w);
                if (lane == 0)
                    gs[j] = 1.f / (1.f + expf(-(pg + GXU[(size_t)bt * DD + j] + cb[j])));
            }
        }
        __syncthreads();

        // ---- region 6: apply top-8 row updates (wave per row) ----
        if (w < TOPK) {
            int row = topI[w];
            size_t doff = ((size_t)(b * MAXD + slotArr[w])) * DD;
            float4 g4 = ((const float4*)gs)[lane];
            float4 x4 = ((const float4*)xs)[lane];
            float4 gd = wasArr[w] ? ((const float4*)(dval + doff))[lane]
                                  : ((const float4*)(memory0 + (size_t)row * DD))[lane];
            float4 r;
            r.x = (1.f - g4.x) * gd.x + g4.x * x4.x;
            r.y = (1.f - g4.y) * gd.y + g4.y * x4.y;
            r.z = (1.f - g4.z) * gd.z + g4.z * x4.z;
            r.w = (1.f - g4.w) * gd.w + g4.w * x4.w;
            ((float4*)(dval + doff))[lane] = r;
        }
        __syncthreads();   // protect LDS before next-iter overwrite
    }
}

extern "C" void kernel_launch(void* const* d_in, const int* in_sizes, int n_in,
                              void* d_out, int out_size, void* d_ws, size_t ws_size,
                              hipStream_t stream) {
    const float* x      = (const float*)d_in[0];
    const float* memory = (const float*)d_in[1];
    const float* Wq     = (const float*)d_in[2];
    const float* bq     = (const float*)d_in[3];
    const float* Wk     = (const float*)d_in[4];
    const float* bk     = (const float*)d_in[5];   (void)bk;   // q.bk cancels in softmax
    const float* Wv     = (const float*)d_in[6];
    const float* bv     = (const float*)d_in[7];
    const float* Wu     = (const float*)d_in[8];
    const float* bu     = (const float*)d_in[9];
    float* out = (float*)d_out;

    float* ws = (float*)d_ws;
    size_t o = 0;
    float* memT  = ws + o; o += (size_t)DD * MM;          // 2 MB
    float* WqT   = ws + o; o += DD * DD;
    float* WulT  = ws + o; o += DD * DD;
    float* WvT   = ws + o; o += DD * DD;
    float* F     = ws + o; o += DD * DD;
    float* cbv   = ws + o; o += DD;
    float* Q     = ws + o; o += (size_t)BB * SS * DD;
    float* QK    = ws + o; o += (size_t)BB * SS * DD;
    float* GXU   = ws + o; o += (size_t)BB * SS * DD;
    float* E     = ws + o; o += (size_t)BB * SS * MM;     // 8 MB
    float* AM0   = ws + o; o += (size_t)BB * SS * DD;     // 1 MB
    float* amAll = ws + o; o += (size_t)BB * SS * DD;     // 1 MB
    float* dval  = ws + o; o += (size_t)BB * MAXD * DD;   // 8 MB

    k_tr<<<dim3(DD / 32, MM / 32), 256, 0, stream>>>(memory, memT, DD, MM);
    k_tr<<<dim3(DD / 32, DD / 32), 256, 0, stream>>>(Wq, WqT, DD, DD);
    k_tr<<<dim3(DD / 32, DD / 32), 256, 0, stream>>>(Wu, WulT, 2 * DD, DD);
    k_tr<<<dim3(DD / 32, DD / 32), 256, 0, stream>>>(Wv, WvT, DD, DD);
    k_gemv<<<BB * SS, 256, 0, stream>>>(x, WqT, bq, Q);
    k_gemv<<<BB * SS, 256, 0, stream>>>(Q, Wk, nullptr, QK);
    k_gemv<<<BB * SS, 256, 0, stream>>>(x, WulT, bu, GXU);
    k_fuse<<<DD, 256, 0, stream>>>(Wu, Wv, bv, F, cbv);
    k_escore<<<dim3(MM / 256, BB * SS / 16), 1024, 0, stream>>>(QK, memT, E);
    k_am0<<<BB * SS / 4, 1024, 0, stream>>>(E, memory, AM0);
    k_persist<<<BB, 1024, 0, stream>>>(x, memory, E, AM0, QK, GXU, F, cbv, dval, amAll);
    k_gemv<<<BB * SS, 256, 0, stream>>>(amAll, WvT, bv, out);   // out = am @ Wv.T + bv
}